// Round 5
// baseline (417.688 us; speedup 1.0000x reference)
//
#include <hip/hip_runtime.h>
#include <math.h>

#define DEVFN __global__ __launch_bounds__(256)

namespace {
constexpr int LL  = 128;   // L
constexpr int MM2 = 255;   // 2L-1
constexpr int NT  = 256;   // ntheta
constexpr int NP  = 512;   // nphi
constexpr int NC  = 32;    // C_IN
constexpr int NO  = 32;    // C_OUT
constexpr float TWO_PI = 6.283185307179586476925286766559f;
}

typedef short v8s __attribute__((ext_vector_type(8)));   // 8 bf16 (4 VGPRs)
typedef float v4f __attribute__((ext_vector_type(4)));   // 4 fp32 acc

__device__ inline unsigned short f2bf(float f) {
  unsigned int u = __float_as_uint(f);
  return (unsigned short)((u + 0x7FFFu + ((u >> 16) & 1u)) >> 16);  // RNE
}

// ---------------------------------------------------------------- KP: prep (twiddles + x transpose)
DEVFN void kp_prep(const float* __restrict__ x, unsigned short* __restrict__ tw1t,
                   unsigned short* __restrict__ vt, unsigned short* __restrict__ xb) {
  __shared__ float sm[32][65];
  const int bid = blockIdx.x;
  const int tid = threadIdx.x;
  const float phi = TWO_PI / (float)NP;
  if (bid < 512) {
    const int idx = bid * 256 + tid;  // 0..131071
    const float fs = TWO_PI / (float)NP;
    {
      const int n = idx >> 9, p = idx & 511;
      const int m = n >> 1;
      const int k = (m * p) & (NP - 1);
      float s, c;
      sincosf(phi * (float)k, &s, &c);
      tw1t[idx] = f2bf((n & 1) ? (-s * fs) : (c * fs));
    }
    {
      const int p = idx >> 8, k = idx & 255;
      const int m = k >> 1;
      const int kk = (m * p) & (NP - 1);
      float s, c;
      sincosf(phi * (float)kk, &s, &c);
      vt[idx] = f2bf((k & 1) ? s : c);
    }
  } else {
    const int q = bid - 512;           // 0..2047
    const int t = q >> 3;
    const int p0 = (q & 7) * 64;
#pragma unroll
    for (int i = 0; i < 8; ++i) {
      const int idx = tid + i * 256;
      const int p = idx >> 5, c = idx & 31;
      sm[c][p] = x[((size_t)t * NP + p0 + p) * NC + c];
    }
    __syncthreads();
    const int c = tid >> 3, pg = tid & 7;
    unsigned short pk[8];
#pragma unroll
    for (int u = 0; u < 8; ++u) pk[u] = f2bf(sm[c][pg * 8 + u]);
    *(uint4*)(xb + ((size_t)(t * 32 + c)) * NP + p0 + pg * 8) = *(const uint4*)pk;
  }
}

// ---------------------------------------------------------------- K1: forward DFT via MFMA
// C[r][n] = sum_p Xb[r][p] * tw1t[n][p];  fw{r,i}[m][t][c] = C * wg[t]
// M=8192, N=256, K=512.  Tile BM=128 x BN=64 -> grid (64,4) = 256 blocks.
DEVFN void k1_mfma(const unsigned short* __restrict__ xb,
                   const unsigned short* __restrict__ tw1t,
                   const float* __restrict__ wg,
                   float* __restrict__ fwr, float* __restrict__ fwi) {
  __shared__ unsigned short As[128 * 32];
  __shared__ unsigned short Bs[64 * 32];
  const int tid = threadIdx.x;
  const int r0 = blockIdx.x * 128;
  const int n0 = blockIdx.y * 64;
  const int wid = tid >> 6, lane = tid & 63;
  const int wm = wid & 1, wn = wid >> 1;   // 2x2 waves, wave tile 64(M) x 32(N)
  v4f acc[4][2];
#pragma unroll
  for (int i = 0; i < 4; ++i)
#pragma unroll
    for (int j = 0; j < 2; ++j) {
      acc[i][j][0] = 0.f; acc[i][j][1] = 0.f; acc[i][j][2] = 0.f; acc[i][j][3] = 0.f;
    }
  const int lr = lane & 15, lk = (lane >> 4) * 8;
  for (int k0 = 0; k0 < 512; k0 += 32) {
#pragma unroll
    for (int s = 0; s < 3; ++s) {
      const int chunk = tid + s * 256;      // 768 chunks x 16B (A:512, B:256)
      if (chunk < 512) {
        const int row = chunk >> 2, c16 = chunk & 3;
        *(uint4*)&As[row * 32 + c16 * 8] =
            *(const uint4*)&xb[(size_t)(r0 + row) * 512 + k0 + c16 * 8];
      } else {
        const int bc = chunk - 512;
        const int row = bc >> 2, c16 = bc & 3;
        *(uint4*)&Bs[row * 32 + c16 * 8] =
            *(const uint4*)&tw1t[(size_t)(n0 + row) * 512 + k0 + c16 * 8];
      }
    }
    __syncthreads();
    v8s af[4], bf[2];
#pragma unroll
    for (int i = 0; i < 4; ++i) af[i] = *(const v8s*)&As[(wm * 64 + i * 16 + lr) * 32 + lk];
#pragma unroll
    for (int j = 0; j < 2; ++j) bf[j] = *(const v8s*)&Bs[(wn * 32 + j * 16 + lr) * 32 + lk];
#pragma unroll
    for (int i = 0; i < 4; ++i)
#pragma unroll
      for (int j = 0; j < 2; ++j)
        acc[i][j] = __builtin_amdgcn_mfma_f32_16x16x32_bf16(af[i], bf[j], acc[i][j], 0, 0, 0);
    __syncthreads();
  }
  const int lrow = (lane >> 4) * 4;
#pragma unroll
  for (int i = 0; i < 4; ++i) {
    const int rbase = r0 + wm * 64 + i * 16 + lrow;
    const int t = rbase >> 5, c0 = rbase & 31;
    const float w = wg[t];
#pragma unroll
    for (int j = 0; j < 2; ++j) {
      const int n = n0 + wn * 32 + j * 16 + lr;
      const int mI = n >> 1;
      float* dst = (n & 1) ? fwi : fwr;
      float4 v = {acc[i][j][0] * w, acc[i][j][1] * w, acc[i][j][2] * w, acc[i][j][3] * w};
      *(float4*)&dst[((size_t)mI * NT + t) * NC + c0] = v;
    }
  }
}

// ---------------------------------------------------------------- K23B: fused flm + mix + partial inverse-Legendre
// Block = (m, q): owns l-set {l = q + 4j, j=0..31} (l >= m contribute; leg rows
// for l < m are exactly zero by construction, so phase A needs no guards).
// Phase A: flm -> LDS (one fw stream feeds 8 l-accumulators per wave).
// Phase B: channel mix (weight stream, guarded to l >= m), y -> LDS.
// Phase C: partial G over this block's l-set -> gp[q][k][r] fp32 (k-major,
// coalesced).  k5 sums the 4 q-partials during staging.
__global__ __launch_bounds__(256, 2) void k23B(
    const float* __restrict__ leg, const float* __restrict__ fwr,
    const float* __restrict__ fwi, const float* __restrict__ wr,
    const float* __restrict__ wi, float* __restrict__ gp) {
  __shared__ float sflm[32][64];   // [j][s*32+c]   8 KB
  __shared__ float sy[32][64];     // [j][part*32+o] 8 KB
  const int bid = blockIdx.x;      // 0..511
  const int m = bid >> 2, q = bid & 3;
  const int tid = threadIdx.x;
  const int wid = tid >> 6, lane = tid & 63;
  const int jmin = (m > q) ? ((m - q + 3) >> 2) : 0;

  // ---- Phase A: flm[l][c,s] for l = q + 4*(wid + 4k), k=0..7
  {
    const int c = lane & 31;
    const float* fp = ((lane >> 5) ? fwi : fwr) + (size_t)m * NT * NC + c;
    const float* lg[8];
#pragma unroll
    for (int k = 0; k < 8; ++k) {
      const int l = q + 4 * (wid + 4 * k);     // 0..127, always in-bounds
      lg[k] = leg + ((size_t)(l * MM2 + 127 + m)) * NT;
    }
    float acc[8] = {};
    for (int t = 0; t < NT; t += 4) {
      const float f0 = fp[(t + 0) * NC];
      const float f1 = fp[(t + 1) * NC];
      const float f2 = fp[(t + 2) * NC];
      const float f3 = fp[(t + 3) * NC];
#pragma unroll
      for (int k = 0; k < 8; ++k) {
        const float4 b = *(const float4*)(lg[k] + t);
        acc[k] = fmaf(b.x, f0, acc[k]);
        acc[k] = fmaf(b.y, f1, acc[k]);
        acc[k] = fmaf(b.z, f2, acc[k]);
        acc[k] = fmaf(b.w, f3, acc[k]);
      }
    }
#pragma unroll
    for (int k = 0; k < 8; ++k) sflm[wid + 4 * k][lane] = acc[k];
  }
  __syncthreads();

  // ---- Phase B: y[l][o] (weight stream; l >= m only — wave-uniform skip)
  {
    const int c8 = lane >> 3, o8 = lane & 7;
    const int c0 = c8 * 4, o0 = o8 * 4;
    const float s0 = (m > 0) ? 1.0f : 0.0f;
    for (int k = 0; k < 8; ++k) {
      const int j = wid + 4 * k;
      const int l = q + 4 * j;
      if (l < m) continue;
      const size_t rp = ((size_t)(l * MM2 + 127 + m) * NC) * NO;
      const size_t rn = ((size_t)(l * MM2 + 127 - m) * NC) * NO;
      float4 accA = {0.f, 0.f, 0.f, 0.f}, accB = {0.f, 0.f, 0.f, 0.f};
#pragma unroll
      for (int i = 0; i < 4; ++i) {
        const int c = c0 + i;
        const float4 wrp = *(const float4*)&wr[rp + (size_t)c * NO + o0];
        const float4 wrn = *(const float4*)&wr[rn + (size_t)c * NO + o0];
        const float4 wip = *(const float4*)&wi[rp + (size_t)c * NO + o0];
        const float4 win = *(const float4*)&wi[rn + (size_t)c * NO + o0];
        const float fa = sflm[j][c];
        const float fb = sflm[j][32 + c];
        float4 wa, wb;
        wa.x = fmaf(s0, wrn.x, wrp.x); wa.y = fmaf(s0, wrn.y, wrp.y);
        wa.z = fmaf(s0, wrn.z, wrp.z); wa.w = fmaf(s0, wrn.w, wrp.w);
        wb.x = fmaf(s0, win.x, -wip.x); wb.y = fmaf(s0, win.y, -wip.y);
        wb.z = fmaf(s0, win.z, -wip.z); wb.w = fmaf(s0, win.w, -wip.w);
        accA.x = fmaf(fa, wa.x, fmaf(fb, wb.x, accA.x));
        accA.y = fmaf(fa, wa.y, fmaf(fb, wb.y, accA.y));
        accA.z = fmaf(fa, wa.z, fmaf(fb, wb.z, accA.z));
        accA.w = fmaf(fa, wa.w, fmaf(fb, wb.w, accA.w));
        accB.x = fmaf(fa, wb.x, fmaf(-fb, wa.x, accB.x));
        accB.y = fmaf(fa, wb.y, fmaf(-fb, wa.y, accB.y));
        accB.z = fmaf(fa, wb.z, fmaf(-fb, wa.z, accB.z));
        accB.w = fmaf(fa, wb.w, fmaf(-fb, wa.w, accB.w));
      }
#pragma unroll
      for (int mask = 8; mask <= 32; mask <<= 1) {
        accA.x += __shfl_xor(accA.x, mask); accA.y += __shfl_xor(accA.y, mask);
        accA.z += __shfl_xor(accA.z, mask); accA.w += __shfl_xor(accA.w, mask);
        accB.x += __shfl_xor(accB.x, mask); accB.y += __shfl_xor(accB.y, mask);
        accB.z += __shfl_xor(accB.z, mask); accB.w += __shfl_xor(accB.w, mask);
      }
      if (c8 == 0) {
        *(float4*)&sy[j][o0] = accA;
        *(float4*)&sy[j][32 + o0] = accB;
      }
    }
  }
  __syncthreads();

  // ---- Phase C: partial G over block's l-set -> gp (k-major, coalesced)
  {
    const int o = tid & 31, tq = tid >> 5;
    float* gq = gp + (size_t)q * (256 * 8192);
    for (int w = 0; w < 8; ++w) {
      const int t0 = w * 32 + tq * 4;
      float aa[4] = {}, bb[4] = {};
      for (int j = jmin; j < 32; ++j) {
        const int l = q + 4 * j;
        const float4 g = *(const float4*)(leg + ((size_t)(l * MM2 + 127 + m)) * NT + t0);
        const float yav = sy[j][o];
        const float ybv = sy[j][32 + o];
        aa[0] = fmaf(g.x, yav, aa[0]);  bb[0] = fmaf(g.x, ybv, bb[0]);
        aa[1] = fmaf(g.y, yav, aa[1]);  bb[1] = fmaf(g.y, ybv, bb[1]);
        aa[2] = fmaf(g.z, yav, aa[2]);  bb[2] = fmaf(g.z, ybv, bb[2]);
        aa[3] = fmaf(g.w, yav, aa[3]);  bb[3] = fmaf(g.w, ybv, bb[3]);
      }
#pragma unroll
      for (int i = 0; i < 4; ++i) {
        const size_t rr = (size_t)(t0 + i) * 32 + o;
        gq[(size_t)(2 * m) * 8192 + rr] = aa[i];
        gq[(size_t)(2 * m + 1) * 8192 + rr] = bb[i];
      }
    }
  }
}

// ---------------------------------------------------------------- K5: inverse DFT via MFMA (A=vt)
// D[p][r] = sum_k vt[p][k] * ut[r][k], where ut[r][k] = sum_q gp[q][k][r]
// (summed fp32 -> bf16 during staging).  BM=256 p x BN=64 r, grid (2,128).
DEVFN void k5_mfma(const float* __restrict__ gp,
                   const unsigned short* __restrict__ vt,
                   float* __restrict__ out) {
  __shared__ unsigned short As[256 * 32];   // vt tile, 16 KB
  __shared__ unsigned short Bs[64 * 32];    // summed ut tile, 4 KB
  const int tid = threadIdx.x;
  const int p0 = blockIdx.x * 256;
  const int r0 = blockIdx.y * 64;
  const int wid = tid >> 6, lane = tid & 63;
  v4f acc[4][4];
#pragma unroll
  for (int i = 0; i < 4; ++i)
#pragma unroll
    for (int j = 0; j < 4; ++j) {
      acc[i][j][0] = 0.f; acc[i][j][1] = 0.f; acc[i][j][2] = 0.f; acc[i][j][3] = 0.f;
    }
  const int lr = lane & 15, lk = (lane >> 4) * 8;
  const int ke = tid >> 3, rq = tid & 7;    // B-gather: k = k0+ke, r = r0+rq*8..+7
  for (int k0 = 0; k0 < 256; k0 += 32) {
#pragma unroll
    for (int s = 0; s < 4; ++s) {
      const int unit = tid + s * 256;       // 1024 units: 256 rows x 4 chunks
      const int row = unit >> 2, c16 = unit & 3;
      *(uint4*)&As[row * 32 + c16 * 8] =
          *(const uint4*)&vt[(size_t)(p0 + row) * 256 + k0 + c16 * 8];
    }
    {
      const size_t base = (size_t)(k0 + ke) * 8192 + r0 + rq * 8;
      float4 s0 = *(const float4*)&gp[base];
      float4 s1 = *(const float4*)&gp[base + 4];
#pragma unroll
      for (int qq = 1; qq < 4; ++qq) {
        const size_t qb = (size_t)qq * (256 * 8192) + base;
        const float4 a0 = *(const float4*)&gp[qb];
        const float4 a1 = *(const float4*)&gp[qb + 4];
        s0.x += a0.x; s0.y += a0.y; s0.z += a0.z; s0.w += a0.w;
        s1.x += a1.x; s1.y += a1.y; s1.z += a1.z; s1.w += a1.w;
      }
      const unsigned short h[8] = {f2bf(s0.x), f2bf(s0.y), f2bf(s0.z), f2bf(s0.w),
                                   f2bf(s1.x), f2bf(s1.y), f2bf(s1.z), f2bf(s1.w)};
#pragma unroll
      for (int i = 0; i < 8; ++i) Bs[(rq * 8 + i) * 32 + ke] = h[i];
    }
    __syncthreads();
    v8s af[4], bf[4];
#pragma unroll
    for (int i = 0; i < 4; ++i) af[i] = *(const v8s*)&As[(wid * 64 + i * 16 + lr) * 32 + lk];
#pragma unroll
    for (int j = 0; j < 4; ++j) bf[j] = *(const v8s*)&Bs[(j * 16 + lr) * 32 + lk];
#pragma unroll
    for (int i = 0; i < 4; ++i)
#pragma unroll
      for (int j = 0; j < 4; ++j)
        acc[i][j] = __builtin_amdgcn_mfma_f32_16x16x32_bf16(af[i], bf[j], acc[i][j], 0, 0, 0);
    __syncthreads();
  }
  const int lrow = (lane >> 4) * 4;
#pragma unroll
  for (int i = 0; i < 4; ++i) {
    const int pbase = p0 + wid * 64 + i * 16 + lrow;
#pragma unroll
    for (int j = 0; j < 4; ++j) {
      const int r = r0 + j * 16 + lr;
      const int t = r >> 5, o = r & 31;
      float4 v = {acc[i][j][0], acc[i][j][1], acc[i][j][2], acc[i][j][3]};
      *(float4*)&out[((size_t)o * NT + t) * NP + pbase] = v;
    }
  }
}

// ---------------------------------------------------------------- launch
extern "C" void kernel_launch(void* const* d_in, const int* in_sizes, int n_in,
                              void* d_out, int out_size, void* d_ws, size_t ws_size,
                              hipStream_t stream) {
  const float* x   = (const float*)d_in[0];
  const float* wr  = (const float*)d_in[1];
  const float* wi  = (const float*)d_in[2];
  const float* leg = (const float*)d_in[3];
  const float* wg  = (const float*)d_in[4];
  float* out = (float*)d_out;

  unsigned short* tw1t = (unsigned short*)d_ws;     // 256*512   = 131072
  unsigned short* vt   = tw1t + 131072;             // 512*256   = 131072
  unsigned short* xb   = vt + 131072;               // 8192*512  = 4194304
  float* fwr = (float*)(xb + 4194304);              // 128*256*32 = 1048576 floats
  float* fwi = fwr + 1048576;
  float* gp  = fwi + 1048576;                       // 4 * 256*8192 = 8388608 floats
                                                    // total ~50.8 MB

  hipLaunchKernelGGL(kp_prep, dim3(2560), dim3(256), 0, stream, x, tw1t, vt, xb);
  hipLaunchKernelGGL(k1_mfma, dim3(64, 4), dim3(256), 0, stream, xb, tw1t, wg, fwr, fwi);
  hipLaunchKernelGGL(k23B, dim3(512), dim3(256), 0, stream, leg, fwr, fwi, wr, wi, gp);
  hipLaunchKernelGGL(k5_mfma, dim3(2, 128), dim3(256), 0, stream, gp, vt, out);
}

// Round 6
// 379.333 us; speedup vs baseline: 1.1011x; 1.1011x over previous
//
#include <hip/hip_runtime.h>
#include <math.h>

#define DEVFN __global__ __launch_bounds__(256)
#define DEVFN4 __global__ __launch_bounds__(256, 4)

namespace {
constexpr int LL  = 128;   // L
constexpr int MM2 = 255;   // 2L-1
constexpr int NT  = 256;   // ntheta
constexpr int NP  = 512;   // nphi
constexpr int NC  = 32;    // C_IN
constexpr int NO  = 32;    // C_OUT
constexpr float TWO_PI = 6.283185307179586476925286766559f;
}

typedef short v8s __attribute__((ext_vector_type(8)));   // 8 bf16 (4 VGPRs)
typedef float v4f __attribute__((ext_vector_type(4)));   // 4 fp32 acc

__device__ inline unsigned short f2bf(float f) {
  unsigned int u = __float_as_uint(f);
  return (unsigned short)((u + 0x7FFFu + ((u >> 16) & 1u)) >> 16);  // RNE
}

// ---------------------------------------------------------------- KP: prep (twiddles + x transpose)
DEVFN void kp_prep(const float* __restrict__ x, unsigned short* __restrict__ tw1t,
                   unsigned short* __restrict__ vt, unsigned short* __restrict__ xb) {
  __shared__ float sm[32][65];
  const int bid = blockIdx.x;
  const int tid = threadIdx.x;
  const float phi = TWO_PI / (float)NP;
  if (bid < 512) {
    const int idx = bid * 256 + tid;  // 0..131071
    const float fs = TWO_PI / (float)NP;
    {
      const int n = idx >> 9, p = idx & 511;
      const int m = n >> 1;
      const int k = (m * p) & (NP - 1);
      float s, c;
      sincosf(phi * (float)k, &s, &c);
      tw1t[idx] = f2bf((n & 1) ? (-s * fs) : (c * fs));
    }
    {
      const int p = idx >> 8, k = idx & 255;
      const int m = k >> 1;
      const int kk = (m * p) & (NP - 1);
      float s, c;
      sincosf(phi * (float)kk, &s, &c);
      vt[idx] = f2bf((k & 1) ? s : c);
    }
  } else {
    const int q = bid - 512;           // 0..2047
    const int t = q >> 3;
    const int p0 = (q & 7) * 64;
#pragma unroll
    for (int i = 0; i < 8; ++i) {
      const int idx = tid + i * 256;
      const int p = idx >> 5, c = idx & 31;
      sm[c][p] = x[((size_t)t * NP + p0 + p) * NC + c];
    }
    __syncthreads();
    const int c = tid >> 3, pg = tid & 7;
    unsigned short pk[8];
#pragma unroll
    for (int u = 0; u < 8; ++u) pk[u] = f2bf(sm[c][pg * 8 + u]);
    *(uint4*)(xb + ((size_t)(t * 32 + c)) * NP + p0 + pg * 8) = *(const uint4*)pk;
  }
}

// ---------------------------------------------------------------- K1: forward DFT via MFMA
// C[r][n] = sum_p Xb[r][p] * tw1t[n][p];  fw{r,i}[m][t][c] = C * wg[t]
// M=8192, N=256, K=512.  BM=64 x BN=64 -> grid (128,4) = 512 blocks (2/CU).
DEVFN4 void k1_mfma(const unsigned short* __restrict__ xb,
                    const unsigned short* __restrict__ tw1t,
                    const float* __restrict__ wg,
                    float* __restrict__ fwr, float* __restrict__ fwi) {
  __shared__ unsigned short As[64 * 32];
  __shared__ unsigned short Bs[64 * 32];
  const int tid = threadIdx.x;
  const int r0 = blockIdx.x * 64;
  const int n0 = blockIdx.y * 64;
  const int wid = tid >> 6, lane = tid & 63;
  const int wm = wid & 1, wn = wid >> 1;   // 2x2 waves, wave tile 32(M) x 32(N)
  v4f acc[2][2];
#pragma unroll
  for (int i = 0; i < 2; ++i)
#pragma unroll
    for (int j = 0; j < 2; ++j) acc[i][j] = (v4f){0.f, 0.f, 0.f, 0.f};
  const int lr = lane & 15, lk = (lane >> 4) * 8;
  const int row = tid >> 2, c16 = tid & 3;
  for (int k0 = 0; k0 < 512; k0 += 32) {
    *(uint4*)&As[row * 32 + c16 * 8] =
        *(const uint4*)&xb[(size_t)(r0 + row) * 512 + k0 + c16 * 8];
    *(uint4*)&Bs[row * 32 + c16 * 8] =
        *(const uint4*)&tw1t[(size_t)(n0 + row) * 512 + k0 + c16 * 8];
    __syncthreads();
    v8s af[2], bf[2];
#pragma unroll
    for (int i = 0; i < 2; ++i) af[i] = *(const v8s*)&As[(wm * 32 + i * 16 + lr) * 32 + lk];
#pragma unroll
    for (int j = 0; j < 2; ++j) bf[j] = *(const v8s*)&Bs[(wn * 32 + j * 16 + lr) * 32 + lk];
#pragma unroll
    for (int i = 0; i < 2; ++i)
#pragma unroll
      for (int j = 0; j < 2; ++j)
        acc[i][j] = __builtin_amdgcn_mfma_f32_16x16x32_bf16(af[i], bf[j], acc[i][j], 0, 0, 0);
    __syncthreads();
  }
  const int lrow = (lane >> 4) * 4;
#pragma unroll
  for (int i = 0; i < 2; ++i) {
    const int rbase = r0 + wm * 32 + i * 16 + lrow;
    const int t = rbase >> 5, c0 = rbase & 31;
    const float w = wg[t];
#pragma unroll
    for (int j = 0; j < 2; ++j) {
      const int n = n0 + wn * 32 + j * 16 + lr;
      const int mI = n >> 1;
      float* dst = (n & 1) ? fwi : fwr;
      float4 v = {acc[i][j][0] * w, acc[i][j][1] * w, acc[i][j][2] * w, acc[i][j][3] * w};
      *(float4*)&dst[((size_t)mI * NT + t) * NC + c0] = v;
    }
  }
}

// ---------------------------------------------------------------- K2: flm (l >= m), 4 l per wave
// One fw stream feeds 4 independent FMA chains.  Grid (128,8) = 1024 blocks,
// (256,4) bounds -> 128 VGPR for deep load pipelining.  fw L2-resident per XCD.
DEVFN4 void k2_flm(const float* __restrict__ leg, const float* __restrict__ fwr,
                   const float* __restrict__ fwi, float* __restrict__ flr,
                   float* __restrict__ fli) {
  const int m = blockIdx.x;
  const int wid = threadIdx.x >> 6, lane = threadIdx.x & 63;
  const int lb = m + blockIdx.y * 16 + wid * 4;   // wave owns lb..lb+3
  if (lb >= LL) return;                           // no barriers below
  const int c = lane & 31;
  const float* fp = ((lane >> 5) ? fwi : fwr) + (size_t)m * NT * NC + c;
  const float* lg[4];
#pragma unroll
  for (int i = 0; i < 4; ++i) {
    const int l = min(lb + i, LL - 1);
    lg[i] = leg + ((size_t)(l * MM2 + 127 + m)) * NT;
  }
  float a[4] = {};
#pragma unroll 2
  for (int t = 0; t < NT; t += 4) {
    const float f0 = fp[(t + 0) * NC];
    const float f1 = fp[(t + 1) * NC];
    const float f2 = fp[(t + 2) * NC];
    const float f3 = fp[(t + 3) * NC];
#pragma unroll
    for (int i = 0; i < 4; ++i) {
      const float4 b = *(const float4*)(lg[i] + t);
      a[i] = fmaf(b.x, f0, a[i]);
      a[i] = fmaf(b.y, f1, a[i]);
      a[i] = fmaf(b.z, f2, a[i]);
      a[i] = fmaf(b.w, f3, a[i]);
    }
  }
  float* outp = (lane >> 5) ? fli : flr;
#pragma unroll
  for (int i = 0; i < 4; ++i)
    if (lb + i < LL) outp[(size_t)(m * LL + lb + i) * NC + c] = a[i];
}

// ---------------------------------------------------------------- K3: channel mix, wave per (m,l)
// Pure weight stream (132 MB read once).  All 16 float4 weight loads issued
// UPFRONT (64 VGPR in flight, single vmcnt wait) -> HBM-BW-bound, not
// latency-bound.  (256,4) bounds give the 128-VGPR budget this needs.
DEVFN4 void k3_mix(const float* __restrict__ flr, const float* __restrict__ fli,
                   const float* __restrict__ wr, const float* __restrict__ wi,
                   float* __restrict__ ya, float* __restrict__ yb) {
  const int m = blockIdx.x;
  const int wid = threadIdx.x >> 6, lane = threadIdx.x & 63;
  const int l = m + blockIdx.y * 4 + wid;
  if (l >= LL) return;
  const int c8 = lane >> 3;          // c-group: c = c8*4 + i
  const int o8 = lane & 7;           // o-quad:  o = o8*4 ..+3
  const int c0 = c8 * 4, o0 = o8 * 4;
  const float s0 = (m > 0) ? 1.0f : 0.0f;
  const size_t rp = ((size_t)(l * MM2 + 127 + m) * NC) * NO;
  const size_t rn = ((size_t)(l * MM2 + 127 - m) * NC) * NO;
  float4 Wrp[4], Wrn[4], Wip[4], Win[4];
#pragma unroll
  for (int i = 0; i < 4; ++i) {
    const size_t co = (size_t)(c0 + i) * NO + o0;
    Wrp[i] = *(const float4*)&wr[rp + co];
    Wrn[i] = *(const float4*)&wr[rn + co];
    Wip[i] = *(const float4*)&wi[rp + co];
    Win[i] = *(const float4*)&wi[rn + co];
  }
  const float4 fa4 = *(const float4*)&flr[(size_t)(m * LL + l) * NC + c0];
  const float4 fb4 = *(const float4*)&fli[(size_t)(m * LL + l) * NC + c0];
  float4 accA = {0.f, 0.f, 0.f, 0.f}, accB = {0.f, 0.f, 0.f, 0.f};
#pragma unroll
  for (int i = 0; i < 4; ++i) {
    const float fa = (i == 0) ? fa4.x : (i == 1) ? fa4.y : (i == 2) ? fa4.z : fa4.w;
    const float fb = (i == 0) ? fb4.x : (i == 1) ? fb4.y : (i == 2) ? fb4.z : fb4.w;
    float4 wa, wb;
    wa.x = fmaf(s0, Wrn[i].x, Wrp[i].x); wa.y = fmaf(s0, Wrn[i].y, Wrp[i].y);
    wa.z = fmaf(s0, Wrn[i].z, Wrp[i].z); wa.w = fmaf(s0, Wrn[i].w, Wrp[i].w);
    wb.x = fmaf(s0, Win[i].x, -Wip[i].x); wb.y = fmaf(s0, Win[i].y, -Wip[i].y);
    wb.z = fmaf(s0, Win[i].z, -Wip[i].z); wb.w = fmaf(s0, Win[i].w, -Wip[i].w);
    accA.x = fmaf(fa, wa.x, fmaf(fb, wb.x, accA.x));
    accA.y = fmaf(fa, wa.y, fmaf(fb, wb.y, accA.y));
    accA.z = fmaf(fa, wa.z, fmaf(fb, wb.z, accA.z));
    accA.w = fmaf(fa, wa.w, fmaf(fb, wb.w, accA.w));
    accB.x = fmaf(fa, wb.x, fmaf(-fb, wa.x, accB.x));
    accB.y = fmaf(fa, wb.y, fmaf(-fb, wa.y, accB.y));
    accB.z = fmaf(fa, wb.z, fmaf(-fb, wa.z, accB.z));
    accB.w = fmaf(fa, wb.w, fmaf(-fb, wa.w, accB.w));
  }
#pragma unroll
  for (int mask = 8; mask <= 32; mask <<= 1) {
    accA.x += __shfl_xor(accA.x, mask); accA.y += __shfl_xor(accA.y, mask);
    accA.z += __shfl_xor(accA.z, mask); accA.w += __shfl_xor(accA.w, mask);
    accB.x += __shfl_xor(accB.x, mask); accB.y += __shfl_xor(accB.y, mask);
    accB.z += __shfl_xor(accB.z, mask); accB.w += __shfl_xor(accB.w, mask);
  }
  if (c8 == 0) {
    *(float4*)&ya[(size_t)(m * LL + l) * NO + o0] = accA;
    *(float4*)&yb[(size_t)(m * LL + l) * NO + o0] = accB;
  }
}

// ---------------------------------------------------------------- K4: inverse Legendre -> Ut bf16
// Ut[r=(t*32+o)][k] : k=2m -> cos coeff, k=2m+1 -> sin coeff.
DEVFN4 void k4_G(const float* __restrict__ leg, const float* __restrict__ ya,
                 const float* __restrict__ yb, unsigned short* __restrict__ ut) {
  const int m = blockIdx.x;
  const int tc = blockIdx.y;
  const int o = threadIdx.x & 31;
  const int tq = threadIdx.x >> 5;
  const int t0 = tc * 32 + tq * 4;
  float aa[4] = {}, bb[4] = {};
#pragma unroll 8
  for (int l = m; l < LL; ++l) {
    const float4 g = *(const float4*)(leg + ((size_t)(l * MM2 + 127 + m)) * NT + t0);
    const float yav = ya[(m * LL + l) * NO + o];
    const float ybv = yb[(m * LL + l) * NO + o];
    aa[0] = fmaf(g.x, yav, aa[0]);  bb[0] = fmaf(g.x, ybv, bb[0]);
    aa[1] = fmaf(g.y, yav, aa[1]);  bb[1] = fmaf(g.y, ybv, bb[1]);
    aa[2] = fmaf(g.z, yav, aa[2]);  bb[2] = fmaf(g.z, ybv, bb[2]);
    aa[3] = fmaf(g.w, yav, aa[3]);  bb[3] = fmaf(g.w, ybv, bb[3]);
  }
#pragma unroll
  for (int i = 0; i < 4; ++i) {
    const unsigned int pk = (unsigned int)f2bf(aa[i]) | ((unsigned int)f2bf(bb[i]) << 16);
    *(unsigned int*)&ut[((size_t)((t0 + i) * 32 + o)) * 256 + 2 * m] = pk;
  }
}

// ---------------------------------------------------------------- K5: inverse DFT via MFMA (A=vt)
// D[p][r] = sum_k vt[p][k] * ut[r][k];  out[o][t][p] = D,  r=t*32+o
// M=512, N=8192, K=256.  BM=64 p x BN=128 r -> grid (8,64) = 512 blocks (2/CU).
DEVFN4 void k5_mfma(const unsigned short* __restrict__ ut,
                    const unsigned short* __restrict__ vt,
                    float* __restrict__ out) {
  __shared__ unsigned short As[64 * 32];   // vt tile (p rows)
  __shared__ unsigned short Bs[128 * 32];  // ut tile (r rows)
  const int tid = threadIdx.x;
  const int p0 = blockIdx.x * 64;
  const int r0 = blockIdx.y * 128;
  const int wid = tid >> 6, lane = tid & 63;
  v4f acc[4][2];
#pragma unroll
  for (int i = 0; i < 4; ++i)
#pragma unroll
    for (int j = 0; j < 2; ++j) acc[i][j] = (v4f){0.f, 0.f, 0.f, 0.f};
  const int lr = lane & 15, lk = (lane >> 4) * 8;
  for (int k0 = 0; k0 < 256; k0 += 32) {
#pragma unroll
    for (int s = 0; s < 3; ++s) {
      const int chunk = tid + s * 256;       // A: 256 chunks, B: 512 chunks
      if (chunk < 256) {
        const int row = chunk >> 2, c16 = chunk & 3;
        *(uint4*)&As[row * 32 + c16 * 8] =
            *(const uint4*)&vt[(size_t)(p0 + row) * 256 + k0 + c16 * 8];
      } else {
        const int bc = chunk - 256;
        const int row = bc >> 2, c16 = bc & 3;
        *(uint4*)&Bs[row * 32 + c16 * 8] =
            *(const uint4*)&ut[(size_t)(r0 + row) * 256 + k0 + c16 * 8];
      }
    }
    __syncthreads();
    v8s af[4], bf[2];
#pragma unroll
    for (int i = 0; i < 4; ++i) af[i] = *(const v8s*)&As[(i * 16 + lr) * 32 + lk];
#pragma unroll
    for (int j = 0; j < 2; ++j) bf[j] = *(const v8s*)&Bs[(wid * 32 + j * 16 + lr) * 32 + lk];
#pragma unroll
    for (int i = 0; i < 4; ++i)
#pragma unroll
      for (int j = 0; j < 2; ++j)
        acc[i][j] = __builtin_amdgcn_mfma_f32_16x16x32_bf16(af[i], bf[j], acc[i][j], 0, 0, 0);
    __syncthreads();
  }
  const int lrow = (lane >> 4) * 4;
#pragma unroll
  for (int i = 0; i < 4; ++i) {
    const int pbase = p0 + i * 16 + lrow;
#pragma unroll
    for (int j = 0; j < 2; ++j) {
      const int r = r0 + wid * 32 + j * 16 + lr;
      const int t = r >> 5, o = r & 31;
      float4 v = {acc[i][j][0], acc[i][j][1], acc[i][j][2], acc[i][j][3]};
      *(float4*)&out[((size_t)o * NT + t) * NP + pbase] = v;
    }
  }
}

// ---------------------------------------------------------------- launch
extern "C" void kernel_launch(void* const* d_in, const int* in_sizes, int n_in,
                              void* d_out, int out_size, void* d_ws, size_t ws_size,
                              hipStream_t stream) {
  const float* x   = (const float*)d_in[0];
  const float* wr  = (const float*)d_in[1];
  const float* wi  = (const float*)d_in[2];
  const float* leg = (const float*)d_in[3];
  const float* wg  = (const float*)d_in[4];
  float* out = (float*)d_out;

  unsigned short* tw1t = (unsigned short*)d_ws;     // 256*512   = 131072
  unsigned short* vt   = tw1t + 131072;             // 512*256   = 131072
  unsigned short* xb   = vt + 131072;               // 8192*512  = 4194304
  unsigned short* ut   = xb + 4194304;              // 8192*256  = 2097152
  float* fwr = (float*)(ut + 2097152);              // 128*256*32 = 1048576
  float* fwi = fwr + 1048576;
  float* flr = fwi + 1048576;                       // 128*128*32 = 524288
  float* fli = flr + 524288;
  float* ya  = fli + 524288;
  float* yb  = ya + 524288;                         // total ~26 MB

  hipLaunchKernelGGL(kp_prep, dim3(2560), dim3(256), 0, stream, x, tw1t, vt, xb);
  hipLaunchKernelGGL(k1_mfma, dim3(128, 4), dim3(256), 0, stream, xb, tw1t, wg, fwr, fwi);
  hipLaunchKernelGGL(k2_flm, dim3(128, 8), dim3(256), 0, stream, leg, fwr, fwi, flr, fli);
  hipLaunchKernelGGL(k3_mix, dim3(128, 32), dim3(256), 0, stream, flr, fli, wr, wi, ya, yb);
  hipLaunchKernelGGL(k4_G, dim3(128, 8), dim3(256), 0, stream, leg, ya, yb, ut);
  hipLaunchKernelGGL(k5_mfma, dim3(8, 64), dim3(256), 0, stream, ut, vt, out);
}